// Round 7
// baseline (5024.603 us; speedup 1.0000x reference)
//
#include <hip/hip_runtime.h>
#include <hip/hip_bf16.h>

// MyRnn: h_t = tanh(emb[idx_t] @ W_xh + b_h + h_{t-1} @ W_hh), 80 steps,
// out = sigmoid(h_80 @ W_out + b_out).
//
// R8: DMA weight stream, spill-proofed.
//  - R7 post-mortem: WRITE_SIZE=1.5GB = scratch. xw-prefetch regs (32 VGPR)
//    live across the whole kstep body + 64 acc > 128-VGPR cap -> acc spilled
//    around every inline-asm wait. The DMA idea itself was sound.
//  - Little's law retro-fit of R2-R6b: 2-deep REGISTER pipelines hold only
//    4-8 outstanding 16B loads/wave = ~0.4B/cy/wave -> 640KB/step needs
//    ~1e5 cy/step (matches R6b's 115k). The weight stream was MLP-starved,
//    never BW-bound. global_load_lds moves 1KB/instruction: 2-slot LDS ring
//    (2x32KB, wave-private slices, no barriers) with counted vmcnt(4).
//  - Fix vs R7: xw loads at STEP START, converted to acc immediately (xw
//    regs die in ~10 instrs; peak live ~115 < 128 -> no spill possible).
//    Compiler's vmcnt(0) drain before the conversion costs ~1 bubble/step.
//  - 16 pure-W ksteps; kstep k: vmcnt(4) | 16 MFMA | lgkmcnt(0) | stage
//    (k+2)&15 (k=14,15 wrap to NEXT step's k0/k1 -- weights t-invariant,
//    DMA stays in flight across the raw-barrier h handoff).
// LDS: hb 64KB (single buffer, 2 raw barriers/step) + wbuf 64KB = 128KB.

#define T_LEN   80
#define EMB_D   100
#define UNITS   512
#define ROWS    64
#define NBLK    32
#define NTHR    512

typedef __bf16 bf16x8 __attribute__((ext_vector_type(8)));
typedef float  f32x4  __attribute__((ext_vector_type(4)));

__device__ __forceinline__ float fast_tanh(float x) {
    float e = __builtin_amdgcn_exp2f(x * 2.8853900817779268f);
    return 1.0f - 2.0f * __builtin_amdgcn_rcpf(1.0f + e);
}

// async global->LDS, 16B per lane; LDS dest is wave-uniform base (HW adds
// lane*16). Compiler does NOT model the LDS write: manual vmcnt discipline.
__device__ __forceinline__ void gload16(const __bf16* g, const __bf16* l) {
    __builtin_amdgcn_global_load_lds(
        (const __attribute__((address_space(1))) unsigned int*)g,
        (__attribute__((address_space(3))) unsigned int*)l, 16, 0, 0);
}

// ---- prep: rewrite weights into MFMA-fragment order in d_ws ----
// FW[w][ks][nt][lane][8]: elem j = Whh[ks*32 + (lane>>4)*8 + j][w*64 + nt*16 + (lane&15)]
// FX[w][ks][nt][lane][8]: same from Wxh, k >= 100 -> 0
__global__ void prep_kernel(const float* __restrict__ Whh,
                            const float* __restrict__ Wxh,
                            __bf16* __restrict__ FW, __bf16* __restrict__ FX) {
    const int f = blockIdx.x * 256 + threadIdx.x;
    if (f < 32768) {
        const int lane = f & 63, nt = (f >> 6) & 3, ks = (f >> 8) & 15, w = f >> 12;
        const int c  = (w << 6) + (nt << 4) + (lane & 15);
        const int kb = (ks << 5) + ((lane >> 4) << 3);
        __bf16* d = FW + (size_t)f * 8;
        #pragma unroll
        for (int j = 0; j < 8; ++j)
            d[j] = (__bf16)Whh[(kb + j) * UNITS + c];
    } else {
        const int f2 = f - 32768;
        const int lane = f2 & 63, nt = (f2 >> 6) & 3, ks = (f2 >> 8) & 3, w = f2 >> 10;
        const int c  = (w << 6) + (nt << 4) + (lane & 15);
        const int kb = (ks << 5) + ((lane >> 4) << 3);
        __bf16* d = FX + (size_t)f2 * 8;
        #pragma unroll
        for (int j = 0; j < 8; ++j)
            d[j] = (kb + j < EMB_D) ? (__bf16)Wxh[(kb + j) * UNITS + c] : (__bf16)0.0f;
    }
}

// ================= fallback kernel (R6b verbatim; used if ws too small) ====

#define MF(A, B, C) __builtin_amdgcn_mfma_f32_16x16x32_bf16((A), (B), (C), 0, 0, 0)

#define PF(KK, P) do {                                                        \
    const __bf16* _p = ((KK) < 4) ? (fxp + ((KK) << 11))                      \
                                  : (fwp + (((KK) - 4) << 11));               \
    P##0 = *(const bf16x8*)(_p);                                              \
    P##1 = *(const bf16x8*)(_p + 512);                                        \
    P##2 = *(const bf16x8*)(_p + 1024);                                       \
    P##3 = *(const bf16x8*)(_p + 1536);                                       \
} while (0)

#define ALD(KK, M) ( ((KK) < 4)                                               \
    ? *(const bf16x8*)&xb_r[xbase + ((M) << 11) + (((KK) ^ kx) << 5)]         \
    : *(const bf16x8*)&hb[hbase + ((M) << 13) + ((((KK) - 4) ^ kx) << 5)] )

#define MM(KK, P) do {                                                        \
    const bf16x8 _a0 = ALD(KK, 0); const bf16x8 _a1 = ALD(KK, 1);             \
    const bf16x8 _a2 = ALD(KK, 2); const bf16x8 _a3 = ALD(KK, 3);             \
    c00 = MF(_a0, P##0, c00); c10 = MF(_a0, P##1, c10);                       \
    c20 = MF(_a0, P##2, c20); c30 = MF(_a0, P##3, c30);                       \
    c01 = MF(_a1, P##0, c01); c11 = MF(_a1, P##1, c11);                       \
    c21 = MF(_a1, P##2, c21); c31 = MF(_a1, P##3, c31);                       \
    c02 = MF(_a2, P##0, c02); c12 = MF(_a2, P##1, c12);                       \
    c22 = MF(_a2, P##2, c22); c32 = MF(_a2, P##3, c32);                       \
    c03 = MF(_a3, P##0, c03); c13 = MF(_a3, P##1, c13);                       \
    c23 = MF(_a3, P##2, c23); c33 = MF(_a3, P##3, c33);                       \
} while (0)

#define HWR(NT_, M_, ACC) {                                                   \
    const int _cc = (wave << 3) + ((NT_) << 1) + (ln >> 3);                   \
    _Pragma("unroll")                                                         \
    for (int _i = 0; _i < 4; ++_i) {                                          \
        const int _rl = (q << 2) + _i;                                        \
        hb[((M_) << 13) + (_rl << 9) + (((_cc ^ (_rl & 7)) << 3) | e7)] =     \
            (__bf16)fast_tanh(ACC[_i]);                                       \
    }                                                                         \
}

#define STEP(XB_R) do {                                                       \
    const __bf16* const xb_r = (XB_R);                                        \
    f32x4 c00 = {bhv0, bhv0, bhv0, bhv0}; f32x4 c01 = c00, c02 = c00, c03 = c00; \
    f32x4 c10 = {bhv1, bhv1, bhv1, bhv1}; f32x4 c11 = c10, c12 = c10, c13 = c10; \
    f32x4 c20 = {bhv2, bhv2, bhv2, bhv2}; f32x4 c21 = c20, c22 = c20, c23 = c20; \
    f32x4 c30 = {bhv3, bhv3, bhv3, bhv3}; f32x4 c31 = c30, c32 = c30, c33 = c30; \
    MM(0,  pA); PF(2,  pA);  MM(1,  pB); PF(3,  pB);                          \
    MM(2,  pA); PF(4,  pA);  MM(3,  pB); PF(5,  pB);                          \
    MM(4,  pA); PF(6,  pA);  MM(5,  pB); PF(7,  pB);                          \
    MM(6,  pA); PF(8,  pA);  MM(7,  pB); PF(9,  pB);                          \
    MM(8,  pA); PF(10, pA);  MM(9,  pB); PF(11, pB);                          \
    MM(10, pA); PF(12, pA);  MM(11, pB); PF(13, pB);                          \
    MM(12, pA); PF(14, pA);  MM(13, pB); PF(15, pB);                          \
    MM(14, pA); PF(16, pA);  MM(15, pB); PF(17, pB);                          \
    MM(16, pA); PF(18, pA);  MM(17, pB); PF(19, pB);                          \
    MM(18, pA); PF(0,  pA);  MM(19, pB); PF(1,  pB);                          \
    __syncthreads();                                                          \
    HWR(0, 0, c00) HWR(0, 1, c01) HWR(0, 2, c02) HWR(0, 3, c03)               \
    HWR(1, 0, c10) HWR(1, 1, c11) HWR(1, 2, c12) HWR(1, 3, c13)               \
    HWR(2, 0, c20) HWR(2, 1, c21) HWR(2, 2, c22) HWR(2, 3, c23)               \
    HWR(3, 0, c30) HWR(3, 1, c31) HWR(3, 2, c32) HWR(3, 3, c33)               \
    __syncthreads();                                                          \
} while (0)

__global__ __launch_bounds__(NTHR)
void rnn_fb(const int*   __restrict__ inputs,
            const float* __restrict__ emb,
            const float* __restrict__ bh,
            const float* __restrict__ Wout,
            const float* __restrict__ bout,
            const __bf16* __restrict__ FW,
            const __bf16* __restrict__ FX,
            float*       __restrict__ out)
{
    __shared__ alignas(16) __bf16 hb[ROWS * UNITS];
    __shared__ alignas(16) __bf16 xbuf[2][ROWS * 128];

    const int tid  = threadIdx.x;
    const int wave = tid >> 6;
    const int lane = tid & 63;
    const int q    = lane >> 4;
    const int ln   = lane & 15;
    const int e7   = ln & 7;
    const int qa   = q ^ (e7 & 3);
    const int kx   = e7 >> 2;
    const int r0   = blockIdx.x * ROWS;

    const float bhv0 = bh[(wave << 6) + 0  + ln];
    const float bhv1 = bh[(wave << 6) + 16 + ln];
    const float bhv2 = bh[(wave << 6) + 32 + ln];
    const float bhv3 = bh[(wave << 6) + 48 + ln];

    const __bf16* const fxp = FX + (wave << 13) + (lane << 3);
    const __bf16* const fwp = FW + (wave << 15) + (lane << 3);
    const int xbase = (ln << 7) + (qa << 3);
    const int hbase = (ln << 9) + (qa << 3);

    bf16x8 pA0, pA1, pA2, pA3;
    bf16x8 pB0, pB1, pB2, pB3;

    {
        int4 z; z.x = z.y = z.z = z.w = 0;
        int4* hp = (int4*)hb;
        #pragma unroll
        for (int i = 0; i < 8; ++i) hp[tid + i * NTHR] = z;
        int4* xp = (int4*)&xbuf[0][0];
        #pragma unroll
        for (int i = 0; i < 4; ++i) xp[tid + i * NTHR] = z;
    }
    __syncthreads();

    auto stage = [&](int t, __bf16* xb) {
        #pragma unroll
        for (int rr = 0; rr < 8; ++rr) {
            const int r = wave + (rr << 3);
            const int idxv = inputs[(r0 + r) * T_LEN + t];
            const float* er = emb + (size_t)idxv * EMB_D;
            const int k0 = lane;
            xb[(r << 7) + ((((k0 >> 3) ^ (r & 7)) << 3) | (k0 & 7))] = (__bf16)er[k0];
            const int k1 = lane + 64;
            if (k1 < EMB_D)
                xb[(r << 7) + ((((k1 >> 3) ^ (r & 7)) << 3) | (k1 & 7))] = (__bf16)er[k1];
        }
    };

    PF(0, pA); PF(1, pB);
    stage(0, xbuf[0]);
    __syncthreads();

    #pragma unroll 1
    for (int t = 0; t < T_LEN; t += 2) {
        stage(t + 1, xbuf[1]);
        STEP(xbuf[0]);
        if (t + 2 < T_LEN) stage(t + 2, xbuf[0]);
        STEP(xbuf[1]);
    }

    #pragma unroll
    for (int rr = 0; rr < 8; ++rr) {
        const int m = (wave << 3) + rr;
        const bf16x8 hv = *(const bf16x8*)&hb[(m << 9) + ((lane ^ (m & 7)) << 3)];
        float s = 0.0f;
        #pragma unroll
        for (int j = 0; j < 8; ++j)
            s += (float)hv[j] * Wout[(lane << 3) + j];
        #pragma unroll
        for (int off = 32; off > 0; off >>= 1)
            s += __shfl_down(s, off, 64);
        if (lane == 0) {
            const float logit = s + bout[0];
            out[r0 + m] = __builtin_amdgcn_rcpf(
                1.0f + __builtin_amdgcn_exp2f(-logit * 1.4426950408889634f));
        }
    }
}

#undef PF
#undef ALD
#undef MM
#undef HWR
#undef STEP

// ===================== fast path: xw precompute + streamed rnn =============

// xw_kernel: XWF[t][blk][wave][m][lane][16] (bf16), j = nt*4 + i holds
//   xw[t][blk*64 + m*16 + (lane>>4)*4 + i][wave*64 + nt*16 + (lane&15)] + bh
__global__ __launch_bounds__(NTHR)
void xw_kernel(const int*   __restrict__ inputs,
               const float* __restrict__ emb,
               const float* __restrict__ bh,
               const __bf16* __restrict__ FX,
               __bf16*      __restrict__ XWF)
{
    __shared__ alignas(16) __bf16 xb[ROWS * 128];

    const int bid  = blockIdx.x;          // 80*32
    const int t    = bid >> 5;
    const int blk  = bid & 31;
    const int tid  = threadIdx.x;
    const int wave = tid >> 6;
    const int lane = tid & 63;
    const int q    = lane >> 4;
    const int ln   = lane & 15;
    const int e7   = ln & 7;
    const int qa   = q ^ (e7 & 3);
    const int kx   = e7 >> 2;
    const int r0   = blk * ROWS;

    {   // zero xbuf (pad cols k>=100 stay 0)
        int4 z; z.x = z.y = z.z = z.w = 0;
        int4* xp = (int4*)xb;
        xp[tid] = z; xp[tid + NTHR] = z;
    }
    __syncthreads();

    #pragma unroll
    for (int rr = 0; rr < 8; ++rr) {
        const int r = wave + (rr << 3);
        const int idxv = inputs[(r0 + r) * T_LEN + t];
        const float* er = emb + (size_t)idxv * EMB_D;
        const int k0 = lane;
        xb[(r << 7) + ((((k0 >> 3) ^ (r & 7)) << 3) | (k0 & 7))] = (__bf16)er[k0];
        const int k1 = lane + 64;
        if (k1 < EMB_D)
            xb[(r << 7) + ((((k1 >> 3) ^ (r & 7)) << 3) | (k1 & 7))] = (__bf16)er[k1];
    }
    __syncthreads();

    const float bhv0 = bh[(wave << 6) + 0  + ln];
    const float bhv1 = bh[(wave << 6) + 16 + ln];
    const float bhv2 = bh[(wave << 6) + 32 + ln];
    const float bhv3 = bh[(wave << 6) + 48 + ln];

    f32x4 c00 = {bhv0, bhv0, bhv0, bhv0}; f32x4 c01 = c00, c02 = c00, c03 = c00;
    f32x4 c10 = {bhv1, bhv1, bhv1, bhv1}; f32x4 c11 = c10, c12 = c10, c13 = c10;
    f32x4 c20 = {bhv2, bhv2, bhv2, bhv2}; f32x4 c21 = c20, c22 = c20, c23 = c20;
    f32x4 c30 = {bhv3, bhv3, bhv3, bhv3}; f32x4 c31 = c30, c32 = c30, c33 = c30;

    const __bf16* const fxp = FX + (wave << 13) + (lane << 3);
    const int xbase = (ln << 7) + (qa << 3);

    #define XSTEP(KS) do {                                                    \
        const bf16x8 b0 = *(const bf16x8*)(fxp + ((KS) << 11));               \
        const bf16x8 b1 = *(const bf16x8*)(fxp + ((KS) << 11) + 512);         \
        const bf16x8 b2 = *(const bf16x8*)(fxp + ((KS) << 11) + 1024);        \
        const bf16x8 b3 = *(const bf16x8*)(fxp + ((KS) << 11) + 1536);        \
        const bf16x8 a0 = *(const bf16x8*)&xb[xbase + 0     + (((KS) ^ kx) << 5)]; \
        const bf16x8 a1 = *(const bf16x8*)&xb[xbase + 2048  + (((KS) ^ kx) << 5)]; \
        const bf16x8 a2 = *(const bf16x8*)&xb[xbase + 4096  + (((KS) ^ kx) << 5)]; \
        const bf16x8 a3 = *(const bf16x8*)&xb[xbase + 6144  + (((KS) ^ kx) << 5)]; \
        c00 = MF(a0, b0, c00); c10 = MF(a0, b1, c10);                         \
        c20 = MF(a0, b2, c20); c30 = MF(a0, b3, c30);                         \
        c01 = MF(a1, b0, c01); c11 = MF(a1, b1, c11);                         \
        c21 = MF(a1, b2, c21); c31 = MF(a1, b3, c31);                         \
        c02 = MF(a2, b0, c02); c12 = MF(a2, b1, c12);                         \
        c22 = MF(a2, b2, c22); c32 = MF(a2, b3, c32);                         \
        c03 = MF(a3, b0, c03); c13 = MF(a3, b1, c13);                         \
        c23 = MF(a3, b2, c23); c33 = MF(a3, b3, c33);                         \
    } while (0)

    XSTEP(0); XSTEP(1); XSTEP(2); XSTEP(3);
    #undef XSTEP

    __bf16* dst = XWF + ((size_t)bid << 15) + (wave << 12) + (lane << 4);
    #define XST(M_, CL0, CL1, CH0, CH1) do {                                  \
        bf16x8 L, H;                                                          \
        L[0] = (__bf16)CL0[0]; L[1] = (__bf16)CL0[1];                         \
        L[2] = (__bf16)CL0[2]; L[3] = (__bf16)CL0[3];                         \
        L[4] = (__bf16)CL1[0]; L[5] = (__bf16)CL1[1];                         \
        L[6] = (__bf16)CL1[2]; L[7] = (__bf16)CL1[3];                         \
        H[0] = (__bf16)CH0[0]; H[1] = (__bf16)CH0[1];                         \
        H[2] = (__bf16)CH0[2]; H[3] = (__bf16)CH0[3];                         \
        H[4] = (__bf16)CH1[0]; H[5] = (__bf16)CH1[1];                         \
        H[6] = (__bf16)CH1[2]; H[7] = (__bf16)CH1[3];                         \
        *(bf16x8*)(dst + ((M_) << 10))     = L;                               \
        *(bf16x8*)(dst + ((M_) << 10) + 8) = H;                               \
    } while (0)
    XST(0, c00, c10, c20, c30);
    XST(1, c01, c11, c21, c31);
    XST(2, c02, c12, c22, c32);
    XST(3, c03, c13, c23, c33);
    #undef XST
}

// raw barrier: drain LDS ops, NOT vmcnt (keeps W-stage DMA in flight)
#define BARX() do { __builtin_amdgcn_sched_barrier(0);                        \
    asm volatile("s_waitcnt lgkmcnt(0)" ::: "memory");                        \
    __builtin_amdgcn_s_barrier();                                             \
    __builtin_amdgcn_sched_barrier(0); } while (0)

// DMA kstep KN's 4 B-frags (this wave's 64-col slice) into wbuf[KN&1]
#define WSTG(KN) do {                                                         \
    const int _k = (KN) & 15;                                                 \
    const int _off = __builtin_amdgcn_readfirstlane(                          \
        (((KN) & 1) << 14) + (wave << 11));                                   \
    const __bf16* _g = fwS + (_k << 11);                                      \
    const __bf16* _l = wb0 + _off;                                            \
    gload16(_g,        _l);                                                   \
    gload16(_g + 512,  _l + 512);                                             \
    gload16(_g + 1024, _l + 1024);                                            \
    gload16(_g + 1536, _l + 1536);                                            \
} while (0)

// consume kstep KS: B from wbuf[KS&1] (wave slice), A from hb, 16 MFMAs
#define KMM(KS) do {                                                          \
    const __bf16* _wb = wb0 + (((KS) & 1) << 14) + (wave << 11) + (lane << 3);\
    const bf16x8 b0 = *(const bf16x8*)(_wb);                                  \
    const bf16x8 b1 = *(const bf16x8*)(_wb + 512);                            \
    const bf16x8 b2 = *(const bf16x8*)(_wb + 1024);                           \
    const bf16x8 b3 = *(const bf16x8*)(_wb + 1536);                           \
    const bf16x8 a0 = *(const bf16x8*)&hb[hbase + 0     + (((KS) ^ kx) << 5)];\
    const bf16x8 a1 = *(const bf16x8*)&hb[hbase + 8192  + (((KS) ^ kx) << 5)];\
    const bf16x8 a2 = *(const bf16x8*)&hb[hbase + 16384 + (((KS) ^ kx) << 5)];\
    const bf16x8 a3 = *(const bf16x8*)&hb[hbase + 24576 + (((KS) ^ kx) << 5)];\
    __builtin_amdgcn_s_setprio(1);                                            \
    c00 = MF(a0, b0, c00); c10 = MF(a0, b1, c10);                             \
    c20 = MF(a0, b2, c20); c30 = MF(a0, b3, c30);                             \
    c01 = MF(a1, b0, c01); c11 = MF(a1, b1, c11);                             \
    c21 = MF(a1, b2, c21); c31 = MF(a1, b3, c31);                             \
    c02 = MF(a2, b0, c02); c12 = MF(a2, b1, c12);                             \
    c22 = MF(a2, b2, c22); c32 = MF(a2, b3, c32);                             \
    c03 = MF(a3, b0, c03); c13 = MF(a3, b1, c13);                             \
    c23 = MF(a3, b2, c23); c33 = MF(a3, b3, c33);                             \
    __builtin_amdgcn_s_setprio(0);                                            \
} while (0)

// kstep: wait current slot landed (k+1's 4 loads may stay in flight),
// consume, drain ds_reads, then DMA slot k+2 (wraps to next step's k0/k1)
#define KSTEP(K) do {                                                         \
    asm volatile("s_waitcnt vmcnt(4)" ::: "memory");                          \
    KMM(K);                                                                   \
    asm volatile("s_waitcnt lgkmcnt(0)" ::: "memory");                        \
    WSTG(((K) + 2) & 15);                                                     \
} while (0)

#define HWR2(NT_, M_, ACC) {                                                  \
    const int _cc = (wave << 3) + ((NT_) << 1) + (ln >> 3);                   \
    _Pragma("unroll")                                                         \
    for (int _i = 0; _i < 4; ++_i) {                                          \
        const int _rl = (q << 2) + _i;                                        \
        hb[((M_) << 13) + (_rl << 9) + (((_cc ^ (_rl & 7)) << 3) | e7)] =     \
            (__bf16)fast_tanh(ACC[_i]);                                       \
    }                                                                         \
}

__global__ __launch_bounds__(NTHR)
void rnn_pre(const float* __restrict__ Wout,
             const float* __restrict__ bout,
             const __bf16* __restrict__ FW,     // frag-order Whh (ws)
             const __bf16* __restrict__ XWF,    // precomputed xw frags (ws)
             float*       __restrict__ out)
{
    // LDS 128KB: hb 64 rows x 512 bf16 (XOR-swizzled, single buffer, 2 raw
    // barriers/step); wbuf 2-slot DMA ring (2x32KB, wave-private slices).
    __shared__ alignas(16) __bf16 hb[ROWS * UNITS];
    __shared__ alignas(16) __bf16 wbuf[2][16384];

    const int tid  = threadIdx.x;
    const int wave = tid >> 6;
    const int lane = tid & 63;
    const int q    = lane >> 4;
    const int ln   = lane & 15;
    const int e7   = ln & 7;
    const int qa   = q ^ (e7 & 3);
    const int kx   = e7 >> 2;
    const int blk  = blockIdx.x;
    const int r0   = blk * ROWS;

    const __bf16* const fwS = FW + (wave << 15) + (lane << 3);
    __bf16* const wb0 = &wbuf[0][0];
    const int hbase = (ln << 9) + (qa << 3);

    // zero h (h0 = 0)
    {
        int4 z; z.x = z.y = z.z = z.w = 0;
        int4* hp = (int4*)hb;
        #pragma unroll
        for (int i = 0; i < 8; ++i) hp[tid + i * NTHR] = z;
    }
    __syncthreads();

    WSTG(0); WSTG(1);     // prologue: slots 0,1 in flight

    #pragma unroll 1
    for (int t = 0; t < T_LEN; ++t) {
        // xw -> acc at STEP START; xw regs die immediately (no spill
        // pressure). Compiler emits a vmcnt drain before the converts --
        // one bubble/step; wbuf slots 0,1 have landed by then.
        const __bf16* _x = XWF + (((size_t)t * NBLK + blk) << 15)
                         + (wave << 12) + (lane << 4);
        const bf16x8 xl0 = *(const bf16x8*)(_x);
        const bf16x8 xh0 = *(const bf16x8*)(_x + 8);
        const bf16x8 xl1 = *(const bf16x8*)(_x + 1024);
        const bf16x8 xh1 = *(const bf16x8*)(_x + 1032);
        const bf16x8 xl2 = *(const bf16x8*)(_x + 2048);
        const bf16x8 xh2 = *(const bf16x8*)(_x + 2056);
        const bf16x8 xl3 = *(const bf16x8*)(_x + 3072);
        const bf16x8 xh3 = *(const bf16x8*)(_x + 3080);

        f32x4 c00 = {(float)xl0[0], (float)xl0[1], (float)xl0[2], (float)xl0[3]};
        f32x4 c10 = {(float)xl0[4], (float)xl0[5], (float)xl0[6], (float)xl0[7]};
        f32x4 c20 = {(float)xh0[0], (float)xh0[1], (float)xh0[2], (float)xh0[3]};
        f32x4 c30 = {(float)xh0[4], (float)xh0[5], (float)xh0[6], (float)xh0[7]};
        f32x4 c01 = {(float)xl1[0], (float)xl1[1], (float)xl1[2], (float)xl1[3]};
        f32x4 c11 = {(float)xl1[4], (float)xl1[5], (float)xl1[6], (float)xl1[7]};
        f32x4 c21 = {(float)xh1[0], (float)xh1[1], (float)xh1[2], (float)xh1[3]};
        f32x4 c31 = {(float)xh1[4], (float)xh1[5], (float)xh1[6], (float)xh1[7]};
        f32x4 c02 = {(float)xl2[0], (float)xl2[1], (float)xl2[2], (float)xl2[3]};
        f32x4 c12 = {(float)xl2[4], (float)xl2[5], (float)xl2[6], (float)xl2[7]};
        f32x4 c22 = {(float)xh2[0], (float)xh2[1], (float)xh2[2], (float)xh2[3]};
        f32x4 c32 = {(float)xh2[4], (float)xh2[5], (float)xh2[6], (float)xh2[7]};
        f32x4 c03 = {(float)xl3[0], (float)xl3[1], (float)xl3[2], (float)xl3[3]};
        f32x4 c13 = {(float)xl3[4], (float)xl3[5], (float)xl3[6], (float)xl3[7]};
        f32x4 c23 = {(float)xh3[0], (float)xh3[1], (float)xh3[2], (float)xh3[3]};
        f32x4 c33 = {(float)xh3[4], (float)xh3[5], (float)xh3[6], (float)xh3[7]};

        KSTEP(0);  KSTEP(1);  KSTEP(2);  KSTEP(3);
        KSTEP(4);  KSTEP(5);  KSTEP(6);  KSTEP(7);
        KSTEP(8);  KSTEP(9);  KSTEP(10); KSTEP(11);
        KSTEP(12); KSTEP(13); KSTEP(14); KSTEP(15);
        // KSTEP(14)/(15) re-staged slots 0/1 = next step's k0/k1: the DMA
        // pipeline crosses the barriers below (raw s_barrier, no vmcnt).

        BARX();    // all hb reads done
        HWR2(0, 0, c00) HWR2(0, 1, c01) HWR2(0, 2, c02) HWR2(0, 3, c03)
        HWR2(1, 0, c10) HWR2(1, 1, c11) HWR2(1, 2, c12) HWR2(1, 3, c13)
        HWR2(2, 0, c20) HWR2(2, 1, c21) HWR2(2, 2, c22) HWR2(2, 3, c23)
        HWR2(3, 0, c30) HWR2(3, 1, c31) HWR2(3, 2, c32) HWR2(3, 3, c33)
        BARX();    // h_t visible
    }

    asm volatile("s_waitcnt vmcnt(0)" ::: "memory");  // drain dangling stages

    // output head: wave w reduces rows 8w .. 8w+7
    #pragma unroll
    for (int rr = 0; rr < 8; ++rr) {
        const int m = (wave << 3) + rr;
        const bf16x8 hv = *(const bf16x8*)&hb[(m << 9) + ((lane ^ (m & 7)) << 3)];
        float s = 0.0f;
        #pragma unroll
        for (int j = 0; j < 8; ++j)
            s += (float)hv[j] * Wout[(lane << 3) + j];
        #pragma unroll
        for (int off = 32; off > 0; off >>= 1)
            s += __shfl_down(s, off, 64);
        if (lane == 0) {
            const float logit = s + bout[0];
            out[r0 + m] = __builtin_amdgcn_rcpf(
                1.0f + __builtin_amdgcn_exp2f(-logit * 1.4426950408889634f));
        }
    }
}

extern "C" void kernel_launch(void* const* d_in, const int* in_sizes, int n_in,
                              void* d_out, int out_size, void* d_ws, size_t ws_size,
                              hipStream_t stream) {
    __bf16* FW  = (__bf16*)d_ws;                  // 512 KB (frag order)
    __bf16* FX  = FW + UNITS * UNITS;             // 128 KB (frag order)
    __bf16* XWF = FX + UNITS * 128;               // 160 MB (xw frags)
    const size_t need = (size_t)(UNITS * UNITS + UNITS * 128) * 2
                      + (size_t)T_LEN * 2048 * UNITS * 2;

    prep_kernel<<<dim3(160), dim3(256), 0, stream>>>(
        (const float*)d_in[3],   // W_hh
        (const float*)d_in[2],   // W_xh
        FW, FX);

    if (ws_size >= need) {
        xw_kernel<<<dim3(T_LEN * NBLK), dim3(NTHR), 0, stream>>>(
            (const int*)d_in[0], (const float*)d_in[1], (const float*)d_in[4],
            FX, XWF);
        rnn_pre<<<dim3(NBLK), dim3(NTHR), 0, stream>>>(
            (const float*)d_in[5], (const float*)d_in[6], FW, XWF,
            (float*)d_out);
    } else {
        rnn_fb<<<dim3(NBLK), dim3(NTHR), 0, stream>>>(
            (const int*)d_in[0], (const float*)d_in[1], (const float*)d_in[4],
            (const float*)d_in[5], (const float*)d_in[6], FW, FX,
            (float*)d_out);
    }
}

// Round 8
// 2154.300 us; speedup vs baseline: 2.3324x; 2.3324x over previous
//
#include <hip/hip_runtime.h>
#include <hip/hip_bf16.h>

// MyRnn: h_t = tanh(emb[idx_t] @ W_xh + b_h + h_{t-1} @ W_hh), 80 steps,
// out = sigmoid(h_80 @ W_out + b_out).
//
// R9: LDS-RESIDENT WEIGHTS + 4-block group h-exchange ("rnn_coop").
// Post-mortem R0-R8: per-MFMA cost ~360-570cy in EVERY variant (scratch,
// reg-stream, DMA-stream) -- B-operand latency fully exposed at 2 waves/
// SIMD; the 640KB/step/CU weight re-read from L2 is structurally latency-
// bound. Fix: never re-read weights. 64 groups x 4 blocks (256 = #CUs,
// 1 block/CU -> co-resident); block (g,s) owns rows [32g..32g+32) x cols
// [128s..128s+128) with its W_hh slice RESIDENT: ksteps 0..13 in LDS
// (112KB, loaded once via global_load_lds), ksteps 14,15 in 16 VGPRs.
// Inner loop: zero global traffic for weights. Groups exchange h via
// global Hbuf[2] (double-buffered by t parity) + per-block monotone flags:
// agent-scope atomic fetch_add (release=wbl2 / acquire=buffer_inv) for
// cross-XCD coherence (G16). xw precomputed full-chip (R7-validated).
// LDS: WL 112KB + hin 32KB + scr 8KB = 152KB. ~90 VGPR.

#define T_LEN   80
#define EMB_D   100
#define UNITS   512

typedef __bf16 bf16x8 __attribute__((ext_vector_type(8)));
typedef __bf16 bf16x4 __attribute__((ext_vector_type(4)));
typedef float  f32x4  __attribute__((ext_vector_type(4)));

#define MF(A, B, C) __builtin_amdgcn_mfma_f32_16x16x32_bf16((A), (B), (C), 0, 0, 0)

__device__ __forceinline__ float fast_tanh(float x) {
    float e = __builtin_amdgcn_exp2f(x * 2.8853900817779268f);
    return 1.0f - 2.0f * __builtin_amdgcn_rcpf(1.0f + e);
}

// async global->LDS, 16B per lane (dest = wave-uniform base + lane*16).
__device__ __forceinline__ void gload16(const __bf16* g, const __bf16* l) {
    __builtin_amdgcn_global_load_lds(
        (const __attribute__((address_space(1))) unsigned int*)g,
        (__attribute__((address_space(3))) unsigned int*)l, 16, 0, 0);
}

// ---- prep: weights -> MFMA-fragment order; zero Hbuf parity0 + flags ----
// FW[w][ks][nt][lane][8]: elem j = Whh[ks*32+(lane>>4)*8+j][w*64+nt*16+(lane&15)]
// FX[w][ks][nt][lane][8]: same from Wxh, k >= 100 -> 0
__global__ void prep_kernel(const float* __restrict__ Whh,
                            const float* __restrict__ Wxh,
                            __bf16* __restrict__ FW, __bf16* __restrict__ FX,
                            __bf16* __restrict__ Hb0, int* __restrict__ flags,
                            int do_coop) {
    const int b = blockIdx.x;
    const int f = b * 256 + threadIdx.x;
    if (b < 128) {                         // FW: 32768 frags
        const int lane = f & 63, nt = (f >> 6) & 3, ks = (f >> 8) & 15, w = f >> 12;
        const int c  = (w << 6) + (nt << 4) + (lane & 15);
        const int kb = (ks << 5) + ((lane >> 4) << 3);
        __bf16* d = FW + (size_t)f * 8;
        #pragma unroll
        for (int j = 0; j < 8; ++j)
            d[j] = (__bf16)Whh[(kb + j) * UNITS + c];
    } else if (b < 160) {                  // FX: 8192 frags
        const int f2 = f - 32768;
        const int lane = f2 & 63, nt = (f2 >> 6) & 3, ks = (f2 >> 8) & 3, w = f2 >> 10;
        const int c  = (w << 6) + (nt << 4) + (lane & 15);
        const int kb = (ks << 5) + ((lane >> 4) << 3);
        __bf16* d = FX + (size_t)f2 * 8;
        #pragma unroll
        for (int j = 0; j < 8; ++j)
            d[j] = (kb + j < EMB_D) ? (__bf16)Wxh[(kb + j) * UNITS + c] : (__bf16)0.0f;
    } else if (do_coop && b < 672) {       // zero Hbuf parity0 (2MB)
        const int idx = (b - 160) * 256 + threadIdx.x;   // < 131072 int4
        int4 z; z.x = z.y = z.z = z.w = 0;
        ((int4*)Hb0)[idx] = z;
    } else if (do_coop && b == 672) {      // zero flags
        if (threadIdx.x < 256) flags[threadIdx.x] = 0;
    }
}

// ===== xw precompute (R7-validated): XWF[t][b64][wave][m][lane][16] ========
// j = nt*4+i holds xw[t][b64*64+m*16+(lane>>4)*4+i][wave*64+nt*16+(lane&15)]+bh
__global__ __launch_bounds__(512)
void xw_kernel(const int*   __restrict__ inputs,
               const float* __restrict__ emb,
               const float* __restrict__ bh,
               const __bf16* __restrict__ FX,
               __bf16*      __restrict__ XWF)
{
    __shared__ alignas(16) __bf16 xb[64 * 128];

    const int bid  = blockIdx.x;          // 80*32
    const int t    = bid >> 5;
    const int blk  = bid & 31;
    const int tid  = threadIdx.x;
    const int wave = tid >> 6;
    const int lane = tid & 63;
    const int q    = lane >> 4;
    const int ln   = lane & 15;
    const int e7   = ln & 7;
    const int qa   = q ^ (e7 & 3);
    const int kx   = e7 >> 2;
    const int r0   = blk * 64;

    {   int4 z; z.x = z.y = z.z = z.w = 0;
        int4* xp = (int4*)xb;
        xp[tid] = z; xp[tid + 512] = z;
    }
    __syncthreads();

    #pragma unroll
    for (int rr = 0; rr < 8; ++rr) {
        const int r = wave + (rr << 3);
        const int idxv = inputs[(r0 + r) * T_LEN + t];
        const float* er = emb + (size_t)idxv * EMB_D;
        const int k0 = lane;
        xb[(r << 7) + ((((k0 >> 3) ^ (r & 7)) << 3) | (k0 & 7))] = (__bf16)er[k0];
        const int k1 = lane + 64;
        if (k1 < EMB_D)
            xb[(r << 7) + ((((k1 >> 3) ^ (r & 7)) << 3) | (k1 & 7))] = (__bf16)er[k1];
    }
    __syncthreads();

    const float bhv0 = bh[(wave << 6) + 0  + ln];
    const float bhv1 = bh[(wave << 6) + 16 + ln];
    const float bhv2 = bh[(wave << 6) + 32 + ln];
    const float bhv3 = bh[(wave << 6) + 48 + ln];

    f32x4 c00 = {bhv0, bhv0, bhv0, bhv0}; f32x4 c01 = c00, c02 = c00, c03 = c00;
    f32x4 c10 = {bhv1, bhv1, bhv1, bhv1}; f32x4 c11 = c10, c12 = c10, c13 = c10;
    f32x4 c20 = {bhv2, bhv2, bhv2, bhv2}; f32x4 c21 = c20, c22 = c20, c23 = c20;
    f32x4 c30 = {bhv3, bhv3, bhv3, bhv3}; f32x4 c31 = c30, c32 = c30, c33 = c30;

    const __bf16* const fxp = FX + (wave << 13) + (lane << 3);
    const int xbase = (ln << 7) + (qa << 3);

    #define XSTEP(KS) do {                                                    \
        const bf16x8 b0 = *(const bf16x8*)(fxp + ((KS) << 11));               \
        const bf16x8 b1 = *(const bf16x8*)(fxp + ((KS) << 11) + 512);         \
        const bf16x8 b2 = *(const bf16x8*)(fxp + ((KS) << 11) + 1024);        \
        const bf16x8 b3 = *(const bf16x8*)(fxp + ((KS) << 11) + 1536);        \
        const bf16x8 a0 = *(const bf16x8*)&xb[xbase + 0     + (((KS) ^ kx) << 5)]; \
        const bf16x8 a1 = *(const bf16x8*)&xb[xbase + 2048  + (((KS) ^ kx) << 5)]; \
        const bf16x8 a2 = *(const bf16x8*)&xb[xbase + 4096  + (((KS) ^ kx) << 5)]; \
        const bf16x8 a3 = *(const bf16x8*)&xb[xbase + 6144  + (((KS) ^ kx) << 5)]; \
        c00 = MF(a0, b0, c00); c10 = MF(a0, b1, c10);                         \
        c20 = MF(a0, b2, c20); c30 = MF(a0, b3, c30);                         \
        c01 = MF(a1, b0, c01); c11 = MF(a1, b1, c11);                         \
        c21 = MF(a1, b2, c21); c31 = MF(a1, b3, c31);                         \
        c02 = MF(a2, b0, c02); c12 = MF(a2, b1, c12);                         \
        c22 = MF(a2, b2, c22); c32 = MF(a2, b3, c32);                         \
        c03 = MF(a3, b0, c03); c13 = MF(a3, b1, c13);                         \
        c23 = MF(a3, b2, c23); c33 = MF(a3, b3, c33);                         \
    } while (0)

    XSTEP(0); XSTEP(1); XSTEP(2); XSTEP(3);
    #undef XSTEP

    __bf16* dst = XWF + ((size_t)bid << 15) + (wave << 12) + (lane << 4);
    #define XST(M_, CL0, CL1, CH0, CH1) do {                                  \
        bf16x8 L, H;                                                          \
        L[0] = (__bf16)CL0[0]; L[1] = (__bf16)CL0[1];                         \
        L[2] = (__bf16)CL0[2]; L[3] = (__bf16)CL0[3];                         \
        L[4] = (__bf16)CL1[0]; L[5] = (__bf16)CL1[1];                         \
        L[6] = (__bf16)CL1[2]; L[7] = (__bf16)CL1[3];                         \
        H[0] = (__bf16)CH0[0]; H[1] = (__bf16)CH0[1];                         \
        H[2] = (__bf16)CH0[2]; H[3] = (__bf16)CH0[3];                         \
        H[4] = (__bf16)CH1[0]; H[5] = (__bf16)CH1[1];                         \
        H[6] = (__bf16)CH1[2]; H[7] = (__bf16)CH1[3];                         \
        *(bf16x8*)(dst + ((M_) << 10))     = L;                               \
        *(bf16x8*)(dst + ((M_) << 10) + 8) = H;                               \
    } while (0)
    XST(0, c00, c10, c20, c30);
    XST(1, c01, c11, c21, c31);
    XST(2, c02, c12, c22, c32);
    XST(3, c03, c13, c23, c33);
    #undef XST
}

// =================== coop kernel: LDS-resident W, group h-exchange =========

__global__ __launch_bounds__(512, 1)
void rnn_coop(const float* __restrict__ Wout,
              const float* __restrict__ bout,
              const __bf16* __restrict__ FW,
              const __bf16* __restrict__ XWF,
              __bf16* __restrict__ Hbuf,       // [2][64][32][512]
              int*    __restrict__ flags,      // [256]
              float*  __restrict__ out)
{
    // LDS 152KB:
    //  WL[k 0..13][wn*2+n][lane][8]   (112KB) -- W_hh slice, frag order
    //  hin[32][512] bf16, XOR-swizzled 16B chunks (chunk ^= row&7 low3)
    //  scr[32][128] bf16, same swizzle (16 chunks/row)
    __shared__ alignas(16) __bf16 WL[14 * 4096];
    __shared__ alignas(16) __bf16 hin[32 * 512];
    __shared__ alignas(16) __bf16 scr[32 * 128];

    const int tid  = threadIdx.x;
    const int wave = tid >> 6;
    const int lane = tid & 63;
    const int q    = lane >> 4;
    const int ln   = lane & 15;
    const int e7   = ln & 7;
    const int qa   = q ^ (e7 & 3);
    const int kx   = e7 >> 2;
    const int wm   = wave >> 2;          // 0..1  rows 16wm..
    const int wn   = wave & 3;           // 0..3  cols 32wn..
    const int bid  = blockIdx.x;
    const int g    = bid >> 2;           // group 0..63 (rows 32g..)
    const int s    = bid & 3;            // slice 0..3 (cols 128s..)

    // ---- fill WL once: wave -> (wnf, nf); 14 x gload16 per wave ----
    {
        const int wnf = wave >> 1, nf = wave & 1;
        const __bf16* src = FW + ((2 * s + (wnf >> 1)) << 15)
                          + (((2 * wnf + nf) & 3) << 9) + (lane << 3);
        const __bf16* dst = WL + (wnf * 2 + nf) * 512;
        #pragma unroll
        for (int k = 0; k < 14; ++k)
            gload16(src + (k << 11), dst + k * 4096);
    }
    // resident ksteps 14,15 (t-invariant, 16 VGPR)
    const __bf16* fws = FW + ((2 * s + (wn >> 1)) << 15) + (lane << 3);
    const bf16x8 r14a = *(const bf16x8*)(fws + (14 << 11) + (((2 * wn + 0) & 3) << 9));
    const bf16x8 r14b = *(const bf16x8*)(fws + (14 << 11) + (((2 * wn + 1) & 3) << 9));
    const bf16x8 r15a = *(const bf16x8*)(fws + (15 << 11) + (((2 * wn + 0) & 3) << 9));
    const bf16x8 r15b = *(const bf16x8*)(fws + (15 << 11) + (((2 * wn + 1) & 3) << 9));

    asm volatile("s_waitcnt vmcnt(0)" ::: "memory");   // WL DMA landed
    __syncthreads();

    const int nt0 = (2 * wn) & 3, nt1 = (2 * wn + 1) & 3;
    const size_t hstr = 32 * 512;
    const int abase = ((16 * wm + ln) << 9) + (qa << 3);

    #pragma unroll 1
    for (int t = 0; t < T_LEN; ++t) {
        // ---- wait peers wrote h_t (flags[peer] >= t); t=0 trivial ----
        if (t > 0) {
            if (tid < 3) {
                int* pf = flags + ((g << 2) + ((s + 1 + tid) & 3));
                long guard = 0; int v;
                do {
                    v = __hip_atomic_fetch_add(pf, 0, __ATOMIC_RELAXED,
                                               __HIP_MEMORY_SCOPE_AGENT);
                } while (v < t && ++guard < 100000000L);
            }
            __syncthreads();
            __builtin_amdgcn_fence(__ATOMIC_ACQUIRE, "agent");  // inv L1/L2
        }
        // ---- stage h_t: Hbuf[t&1][g] -> hin (swizzled) ----
        {
            const __bf16* hs = Hbuf + (size_t)((t & 1) * 64 + g) * hstr;
            #pragma unroll
            for (int j = 0; j < 4; ++j) {
                const int id = tid + (j << 9);
                const int r = id >> 6, c = id & 63;
                const bf16x8 v = *(const bf16x8*)(hs + (r << 9) + (c << 3));
                const int cs = (c & ~7) | ((c ^ (r & 7)) & 7);
                *(bf16x8*)&hin[(r << 9) + (cs << 3)] = v;
            }
        }
        __syncthreads();
        // ---- acc init from xw frags ----
        const __bf16* xp = XWF + ((size_t)(t * 32 + (g >> 1)) << 15)
                         + ((2 * s + (wn >> 1)) << 12)
                         + ((2 * (g & 1) + wm) << 10) + (lane << 4);
        const bf16x4 xa = *(const bf16x4*)(xp + 4 * nt0);
        const bf16x4 xb4 = *(const bf16x4*)(xp + 4 * nt1);
        f32x4 c0 = {(float)xa[0], (float)xa[1], (float)xa[2], (float)xa[3]};
        f32x4 c1 = {(float)xb4[0], (float)xb4[1], (float)xb4[2], (float)xb4[3]};
        // ---- 16 ksteps, all operands LDS/VGPR ----
        #pragma unroll
        for (int k = 0; k < 14; ++k) {
            const bf16x8 A  = *(const bf16x8*)&hin[abase + ((k ^ kx) << 5)];
            const bf16x8 B0 = *(const bf16x8*)&WL[k * 4096 + (wn * 2 + 0) * 512 + (lane << 3)];
            const bf16x8 B1 = *(const bf16x8*)&WL[k * 4096 + (wn * 2 + 1) * 512 + (lane << 3)];
            c0 = MF(A, B0, c0); c1 = MF(A, B1, c1);
        }
        {   const bf16x8 A = *(const bf16x8*)&hin[abase + ((14 ^ kx) << 5)];
            c0 = MF(A, r14a, c0); c1 = MF(A, r14b, c1); }
        {   const bf16x8 A = *(const bf16x8*)&hin[abase + ((15 ^ kx) << 5)];
            c0 = MF(A, r15a, c0); c1 = MF(A, r15b, c1); }
        // ---- h' -> scr (swizzled scalar writes; C/D row = 4q+i, col = ln) ----
        #pragma unroll
        for (int i = 0; i < 4; ++i) {
            const int row = 16 * wm + 4 * q + i;
            const int ch0 = 4 * wn + 0 + (ln >> 3);
            const int ch1 = 4 * wn + 2 + (ln >> 3);
            const int s0 = (ch0 & 8) | ((ch0 ^ (row & 7)) & 7);
            const int s1 = (ch1 & 8) | ((ch1 ^ (row & 7)) & 7);
            scr[(row << 7) + (s0 << 3) + (ln & 7)] = (__bf16)fast_tanh(c0[i]);
            scr[(row << 7) + (s1 << 3) + (ln & 7)] = (__bf16)fast_tanh(c1[i]);
        }
        __syncthreads();
        // ---- scr -> Hbuf[(t+1)&1][g] rows r, cols [128s..) row-major ----
        {
            const int r = tid >> 4, c = tid & 15;
            const int cs = (c & 8) | ((c ^ (r & 7)) & 7);
            const bf16x8 v = *(const bf16x8*)&scr[(r << 7) + (cs << 3)];
            __bf16* hd = Hbuf + (size_t)(((t + 1) & 1) * 64 + g) * hstr
                       + (r << 9) + (s << 7) + (c << 3);
            *(bf16x8*)hd = v;
        }
        __syncthreads();   // drains vmcnt: stores visible at L2
        if (tid == 0)
            __hip_atomic_fetch_add(flags + bid, 1, __ATOMIC_RELEASE,
                                   __HIP_MEMORY_SCOPE_AGENT);   // flag = t+1
    }

    // ---- output head: s==0 blocks gather full h_80 and reduce ----
    if (s == 0) {
        if (tid < 3) {
            int* pf = flags + ((g << 2) + 1 + tid);
            long guard = 0; int v;
            do {
                v = __hip_atomic_fetch_add(pf, 0, __ATOMIC_RELAXED,
                                           __HIP_MEMORY_SCOPE_AGENT);
            } while (v < T_LEN && ++guard < 100000000L);
        }
        __syncthreads();
        __builtin_amdgcn_fence(__ATOMIC_ACQUIRE, "agent");
        {   // stage h_80 (parity 0)
            const __bf16* hs = Hbuf + (size_t)(0 * 64 + g) * hstr;
            #pragma unroll
            for (int j = 0; j < 4; ++j) {
                const int id = tid + (j << 9);
                const int r = id >> 6, c = id & 63;
                const bf16x8 v = *(const bf16x8*)(hs + (r << 9) + (c << 3));
                const int cs = (c & ~7) | ((c ^ (r & 7)) & 7);
                *(bf16x8*)&hin[(r << 9) + (cs << 3)] = v;
            }
        }
        __syncthreads();
        // wave w reduces rows 4w..4w+3
        #pragma unroll
        for (int rr = 0; rr < 4; ++rr) {
            const int m = (wave << 2) + rr;
            const int sw = (lane & ~7) | ((lane ^ (m & 7)) & 7);
            const bf16x8 hv = *(const bf16x8*)&hin[(m << 9) + (sw << 3)];
            float sum = 0.0f;
            #pragma unroll
            for (int jj = 0; jj < 8; ++jj)
                sum += (float)hv[jj] * Wout[(lane << 3) + jj];
            #pragma unroll
            for (int off = 32; off > 0; off >>= 1)
                sum += __shfl_down(sum, off, 64);
            if (lane == 0) {
                const float logit = sum + bout[0];
                out[(g << 5) + m] = __builtin_amdgcn_rcpf(
                    1.0f + __builtin_amdgcn_exp2f(-logit * 1.4426950408889634f));
            }
        }
    }
}

// ================= fallback (R6b verbatim; used only if ws too small) ======

#define FPF(KK, P) do {                                                       \
    const __bf16* _p = ((KK) < 4) ? (fxp + ((KK) << 11))                      \
                                  : (fwp + (((KK) - 4) << 11));               \
    P##0 = *(const bf16x8*)(_p);                                              \
    P##1 = *(const bf16x8*)(_p + 512);                                        \
    P##2 = *(const bf16x8*)(_p + 1024);                                       \
    P##3 = *(const bf16x8*)(_p + 1536);                                       \
} while (0)

#define FALD(KK, M) ( ((KK) < 4)                                              \
    ? *(const bf16x8*)&xb_r[xbase + ((M) << 11) + (((KK) ^ kx) << 5)]         \
    : *(const bf16x8*)&hb[hbase + ((M) << 13) + ((((KK) - 4) ^ kx) << 5)] )

#define FMM(KK, P) do {                                                       \
    const bf16x8 _a0 = FALD(KK, 0); const bf16x8 _a1 = FALD(KK, 1);           \
    const bf16x8 _a2 = FALD(KK, 2); const bf16x8 _a3 = FALD(KK, 3);           \
    c00 = MF(_a0, P##0, c00); c10 = MF(_a0, P##1, c10);                       \
    c20 = MF(_a0, P##2, c20); c30 = MF(_a0, P##3, c30);                       \
    c01 = MF(_a1, P##0, c01); c11 = MF(_a1, P##1, c11);                       \
    c21 = MF(_a1, P##2, c21); c31 = MF(_a1, P##3, c31);                       \
    c02 = MF(_a2, P##0, c02); c12 = MF(_a2, P##1, c12);                       \
    c22 = MF(_a2, P##2, c22); c32 = MF(_a2, P##3, c32);                       \
    c03 = MF(_a3, P##0, c03); c13 = MF(_a3, P##1, c13);                       \
    c23 = MF(_a3, P##2, c23); c33 = MF(_a3, P##3, c33);                       \
} while (0)

#define FHWR(NT_, M_, ACC) {                                                  \
    const int _cc = (wave << 3) + ((NT_) << 1) + (ln >> 3);                   \
    _Pragma("unroll")                                                         \
    for (int _i = 0; _i < 4; ++_i) {                                          \
        const int _rl = (q << 2) + _i;                                        \
        hb[((M_) << 13) + (_rl << 9) + (((_cc ^ (_rl & 7)) << 3) | e7)] =     \
            (__bf16)fast_tanh(ACC[_i]);                                       \
    }                                                                         \
}

#define FSTEP(XB_R) do {                                                      \
    const __bf16* const xb_r = (XB_R);                                        \
    f32x4 c00 = {bhv0, bhv0, bhv0, bhv0}; f32x4 c01 = c00, c02 = c00, c03 = c00; \
    f32x4 c10 = {bhv1, bhv1, bhv1, bhv1}; f32x4 c11 = c10, c12 = c10, c13 = c10; \
    f32x4 c20 = {bhv2, bhv2, bhv2, bhv2}; f32x4 c21 = c20, c22 = c20, c23 = c20; \
    f32x4 c30 = {bhv3, bhv3, bhv3, bhv3}; f32x4 c31 = c30, c32 = c30, c33 = c30; \
    FMM(0,  pA); FPF(2,  pA);  FMM(1,  pB); FPF(3,  pB);                      \
    FMM(2,  pA); FPF(4,  pA);  FMM(3,  pB); FPF(5,  pB);                      \
    FMM(4,  pA); FPF(6,  pA);  FMM(5,  pB); FPF(7,  pB);                      \
    FMM(6,  pA); FPF(8,  pA);  FMM(7,  pB); FPF(9,  pB);                      \
    FMM(8,  pA); FPF(10, pA);  FMM(9,  pB); FPF(11, pB);                      \
    FMM(10, pA); FPF(12, pA);  FMM(11, pB); FPF(13, pB);                      \
    FMM(12, pA); FPF(14, pA);  FMM(13, pB); FPF(15, pB);                      \
    FMM(14, pA); FPF(16, pA);  FMM(15, pB); FPF(17, pB);                      \
    FMM(16, pA); FPF(18, pA);  FMM(17, pB); FPF(19, pB);                      \
    FMM(18, pA); FPF(0,  pA);  FMM(19, pB); FPF(1,  pB);                      \
    __syncthreads();                                                          \
    FHWR(0, 0, c00) FHWR(0, 1, c01) FHWR(0, 2, c02) FHWR(0, 3, c03)           \
    FHWR(1, 0, c10) FHWR(1, 1, c11) FHWR(1, 2, c12) FHWR(1, 3, c13)           \
    FHWR(2, 0, c20) FHWR(2, 1, c21) FHWR(2, 2, c22) FHWR(2, 3, c23)           \
    FHWR(3, 0, c30) FHWR(3, 1, c31) FHWR(3, 2, c32) FHWR(3, 3, c33)           \
    __syncthreads();                                                          \
} while (0)

__global__ __launch_bounds__(512)
void rnn_fb(const int*   __restrict__ inputs,
            const float* __restrict__ emb,
            const float* __restrict__ bh,
            const float* __restrict__ Wout,
            const float* __restrict__ bout,
            const __bf16* __restrict__ FW,
            const __bf16* __restrict__ FX,
            float*       __restrict__ out)
{
    __shared__ alignas(16) __bf16 hb[64 * UNITS];
    __shared__ alignas(16) __bf16 xbuf[2][64 * 128];

    const int tid  = threadIdx.x;
    const int wave = tid >> 6;
    const int lane = tid & 63;
    const int q    = lane >> 4;
    const int ln   = lane & 15;
    const int e7   = ln & 7;
    const int qa   = q ^ (e7 & 3);
    const int kx   = e7 >> 2;
    const int r0   = blockIdx.x * 64;

    const float bhv0 = bh[(wave << 6) + 0  + ln];
    const float bhv1 = bh[(wave << 6) + 16 + ln];
    const float bhv2 = bh[(wave << 6) + 32 + ln];
    const float bhv3 = bh[(wave << 6) + 48 + ln];

    const __bf16* const fxp = FX + (wave << 13) + (lane << 3);
    const __bf16* const fwp = FW + (wave << 15) + (lane << 3);
    const int xbase = (ln << 7) + (qa << 3);
    const int hbase = (ln << 9) + (qa << 3);

    bf16x8 pA0, pA1, pA2, pA3;
    bf16x8 pB0, pB1, pB2, pB3;

    {
        int4 z; z.x = z.y = z.z = z.w = 0;
        int4* hp = (int4*)hb;
        #pragma unroll
        for (int i = 0; i < 8; ++i) hp[tid + i * 512] = z;
        int4* xp = (int4*)&xbuf[0][0];
        #pragma unroll
        for (int i = 0; i < 4; ++i) xp[tid + i * 512] = z;
    }
    __syncthreads();

    auto stage = [&](int t, __bf16* xb) {
        #pragma unroll
        for (int rr = 0; rr < 8; ++rr) {
            const int r = wave + (rr << 3);
            const int idxv = inputs[(r0 + r) * T_LEN + t];
            const float* er = emb + (size_t)idxv * EMB_D;
            const int k0 = lane;
            xb[(r << 7) + ((((k0 >> 3) ^ (r & 7)) << 3) | (k0 & 7))] = (__bf16)er[k0];
            const int k1 = lane + 64;
            if (k1 < EMB_D)
                xb[(r << 7) + ((((k1 >> 3) ^ (r & 7)) << 3) | (k1 & 7))] = (__bf16)er[k1];
        }
    };

    FPF(0, pA); FPF(1, pB);
    stage(0, xbuf[0]);
    __syncthreads();

    #pragma unroll 1
    for (int t = 0; t < T_LEN; t += 2) {
        stage(t + 1, xbuf[1]);
        FSTEP(xbuf[0]);
        if (t + 2 < T_LEN) stage(t + 2, xbuf[0]);
        FSTEP(xbuf[1]);
    }

    #pragma unroll
    for (int rr = 0; rr < 8; ++rr) {
        const int m = (wave << 3) + rr;
        const bf16x8 hv = *(const bf16x8*)&hb[(m << 9) + ((lane ^ (m & 7)) << 3)];
        float s = 0.0f;
        #pragma unroll
        for (int j = 0; j < 8; ++j)
            s += (float)hv[j] * Wout[(lane << 3) + j];
        #pragma unroll
        for (int off = 32; off > 0; off >>= 1)
            s += __shfl_down(s, off, 64);
        if (lane == 0) {
            const float logit = s + bout[0];
            out[r0 + m] = __builtin_amdgcn_rcpf(
                1.0f + __builtin_amdgcn_exp2f(-logit * 1.4426950408889634f));
        }
    }
}

extern "C" void kernel_launch(void* const* d_in, const int* in_sizes, int n_in,
                              void* d_out, int out_size, void* d_ws, size_t ws_size,
                              hipStream_t stream) {
    // d_ws layout (bf16 elems): FW 262144 | FX 65536 | Hbuf 2*1048576 |
    // flags 512 (256 ints) | XWF 83886080
    __bf16* FW    = (__bf16*)d_ws;
    __bf16* FX    = FW + 262144;
    __bf16* Hbuf  = FX + 65536;
    int*    flags = (int*)(Hbuf + 2097152);
    __bf16* XWF   = (__bf16*)(flags + 256);
    const size_t need = ((size_t)262144 + 65536 + 2097152 + 512 + 83886080) * 2;
    const int coop = (ws_size >= need);

    prep_kernel<<<dim3(coop ? 673 : 160), dim3(256), 0, stream>>>(
        (const float*)d_in[3],   // W_hh
        (const float*)d_in[2],   // W_xh
        FW, FX, Hbuf, flags, coop);

    if (coop) {
        xw_kernel<<<dim3(T_LEN * 32), dim3(512), 0, stream>>>(
            (const int*)d_in[0], (const float*)d_in[1], (const float*)d_in[4],
            FX, XWF);
        rnn_coop<<<dim3(256), dim3(512), 0, stream>>>(
            (const float*)d_in[5], (const float*)d_in[6],
            FW, XWF, Hbuf, flags, (float*)d_out);
    } else {
        rnn_fb<<<dim3(32), dim3(512), 0, stream>>>(
            (const int*)d_in[0], (const float*)d_in[1], (const float*)d_in[4],
            (const float*)d_in[5], (const float*)d_in[6], FW, FX,
            (float*)d_out);
    }
}